// Round 12
// baseline (235.134 us; speedup 1.0000x reference)
//
#include <hip/hip_runtime.h>
#include <hip/hip_bf16.h>
#include <math.h>
#include <stdint.h>

// Problem constants: B=2, S=2048, D=1024, H=16, DK=64
constexpr int Bb = 2, Ss = 2048, Dd = 1024, Hh = 16;
constexpr int Mm = Bb * Ss;  // 4096 (GEMM M)
constexpr int Nn = Dd;       // 1024
constexpr int Kk = Dd;       // 1024
// fold 1/sqrt(DK) and log2(e) into Q so the softmax uses exp2
constexpr float QSCALE = 0.125f * 1.44269504088896340736f;

typedef unsigned short ushort_t;
typedef __attribute__((ext_vector_type(8))) short bf16x8;   // K=32 A/B frag
typedef __attribute__((ext_vector_type(4))) float f32x4;    // 16x16 C/D frag

#if __has_builtin(__builtin_amdgcn_exp2f)
#define EXP2F(x) __builtin_amdgcn_exp2f(x)
#else
#define EXP2F(x) exp2f(x)
#endif

__device__ __forceinline__ ushort_t f2bf(float f) {  // round-to-nearest-even
  union { float f; unsigned u; } v; v.f = f;
  return (ushort_t)((v.u + 0x7fff + ((v.u >> 16) & 1)) >> 16);
}

// async global->LDS, 16B per lane; LDS dest is wave-uniform base + lane*16
__device__ __forceinline__ void load16_lds(const void* g, void* l) {
  __builtin_amdgcn_global_load_lds(
      (const __attribute__((address_space(1))) void*)(uintptr_t)g,
      (__attribute__((address_space(3))) void*)(uint32_t)(uintptr_t)l, 16, 0, 0);
}

// ---------------------------------------------------------------------------
// Merged prep pass (one dispatch):
//  blocks [0, 12288): fp32->bf16 convert of q,k,v  (z = bid/4096)
//  blocks [12288, 13312): W [K][N] fp32 -> Wt [N][K] bf16 transpose
// ---------------------------------------------------------------------------
__global__ __launch_bounds__(256) void prep(
    const float* __restrict__ q, const float* __restrict__ k,
    const float* __restrict__ v, ushort_t* __restrict__ qkvb,
    const float* __restrict__ Wq, const float* __restrict__ Wk,
    const float* __restrict__ Wv, const float* __restrict__ Wo,
    ushort_t* __restrict__ Wt) {
  const int bid = blockIdx.x;
  const int tid = threadIdx.x;
  if (bid < 12288) {  // ---- convert q/k/v ----
    const int z = bid >> 12, xi = bid & 4095;
    const float* src = (z == 0) ? q : (z == 1) ? k : v;
    ushort_t* dst = qkvb + (size_t)z * Mm * Kk;
    const size_t idx = ((size_t)xi * 256 + tid) * 4;
    const float4 val = *(const float4*)(src + idx);
    ushort4 o;
    o.x = f2bf(val.x); o.y = f2bf(val.y); o.z = f2bf(val.z); o.w = f2bf(val.w);
    *(ushort4*)(dst + idx) = o;
    return;
  }
  // ---- transpose weights ----
  const int bid2 = bid - 12288;
  const int z = bid2 >> 8, rem = bid2 & 255;
  const float* W = (z == 0) ? Wq : (z == 1) ? Wk : (z == 2) ? Wv : Wo;
  ushort_t* out = Wt + (size_t)z * Kk * Nn;
  __shared__ float t[64][65];
  const int n0 = (rem & 15) * 64, k0 = (rem >> 4) * 64;
  const int lr = tid >> 4, lc = (tid & 15) * 4;
#pragma unroll
  for (int i = 0; i < 4; i++) {
    const int r = lr + i * 16;
    const float4 vv = *(const float4*)(W + (size_t)(k0 + r) * Nn + n0 + lc);
    t[r][lc] = vv.x; t[r][lc + 1] = vv.y; t[r][lc + 2] = vv.z; t[r][lc + 3] = vv.w;
  }
  __syncthreads();
  const int n = tid >> 2, kc = (tid & 3) * 16;
  ushort_t tmp[16];
#pragma unroll
  for (int j = 0; j < 16; j++) tmp[j] = f2bf(t[kc + j][n]);
  ushort_t* op = out + (size_t)(n0 + n) * Kk + k0 + kc;
  ((uint4*)op)[0] = ((uint4*)tmp)[0];
  ((uint4*)op)[1] = ((uint4*)tmp)[1];
}

// ---------------------------------------------------------------------------
// bf16 MFMA GEMM, m97 recipe + XCD-aware (x,y) swizzle within each z-slice.
// v14 wrote V^T directly in the z==2 epilogue but with 4KB-stride scattered
// 8B stores (64 cache lines per inst) — neutral vs the separate transpose.
// v15 keeps the fused V^T write but COALESCES it through the (dead) staging
// LDS: 4 rounds of 32 d x 128 tokens; active waves drop acc fragments as
// 8B s-contiguous runs into padded LDS rows, then 256 threads stream 32B
// each -> 256B coalesced V^T rows. transpose_v dispatch + its 16MB HBM
// round-trip stay eliminated.
// ---------------------------------------------------------------------------
template <int BN, bool OUT_BF16, bool VT_Z2>
__global__ __launch_bounds__(256) void gemm_mfma(
    const ushort_t* __restrict__ Abase, size_t a_stride,
    const ushort_t* __restrict__ Wbase, size_t w_stride,
    const float* __restrict__ bias0, const float* __restrict__ bias1,
    const float* __restrict__ bias2, void* __restrict__ Cbase, size_t c_stride,
    float scale_z0, ushort_t* __restrict__ vt_out) {
  constexpr int BM = 128, BK = 32;
  constexpr int WM = (BN == 128) ? 64 : 32;  // wave tile
  constexpr int MT_ = WM / 16, NT_ = 4;      // WN = 64 always
  __shared__ ushort_t smemAB[(BM + BN) * BK];  // As || Bs (contiguous)
  ushort_t* As = smemAB;
  ushort_t* Bs = smemAB + BM * BK;
  const int tid = threadIdx.x, lane = tid & 63, wid = tid >> 6;
  const int z = blockIdx.z;
  const ushort_t* A = Abase + (size_t)z * a_stride;
  const ushort_t* Wt = Wbase + (size_t)z * w_stride;
  const float* bias = (z == 0) ? bias0 : (z == 1) ? bias1 : bias2;
  const float sc = (z == 0) ? scale_z0 : 1.0f;
  // XCD-aware swizzle (bijective: nxy % 8 == 0)
  const int nxy = gridDim.x * gridDim.y;
  const int lid0 = blockIdx.x + gridDim.x * blockIdx.y;
  const int cpx = nxy >> 3;
  const int swb = (lid0 & 7) * cpx + (lid0 >> 3);
  const int m0 = (swb / gridDim.x) * BM, n0 = (swb % gridDim.x) * BN;
  const int wm = (BN == 128) ? (wid >> 1) * 64 : wid * 32;
  const int wn = (BN == 128) ? (wid & 1) * 64 : 0;
  const int quad = lane >> 4, r16 = lane & 15;
  const int srow = lane >> 2;        // staging: 16 rows/inst
  const int scol = (lane & 3) * 8;   // 4 lanes x 16B per 64B row

  f32x4 acc[MT_][NT_];
#pragma unroll
  for (int m = 0; m < MT_; m++)
#pragma unroll
    for (int n = 0; n < NT_; n++) acc[m][n] = f32x4{0.f, 0.f, 0.f, 0.f};

  for (int k0 = 0; k0 < Kk; k0 += BK) {
    __syncthreads();
#pragma unroll
    for (int i = 0; i < BM / 64; i++) {
      const int I = wid * (BM / 64) + i;
      load16_lds(A + (size_t)(m0 + I * 16 + srow) * Kk + k0 + scol, As + I * 512);
    }
#pragma unroll
    for (int i = 0; i < BN / 64; i++) {
      const int I = wid * (BN / 64) + i;
      load16_lds(Wt + (size_t)(n0 + I * 16 + srow) * Kk + k0 + scol, Bs + I * 512);
    }
    __syncthreads();
    bf16x8 af[MT_], bfr[NT_];
#pragma unroll
    for (int m = 0; m < MT_; m++)
      af[m] = *(const bf16x8*)(As + (wm + m * 16 + r16) * BK + quad * 8);
#pragma unroll
    for (int n = 0; n < NT_; n++)
      bfr[n] = *(const bf16x8*)(Bs + (wn + n * 16 + r16) * BK + quad * 8);
#pragma unroll
    for (int m = 0; m < MT_; m++)
#pragma unroll
      for (int n = 0; n < NT_; n++)
        acc[m][n] =
            __builtin_amdgcn_mfma_f32_16x16x32_bf16(af[m], bfr[n], acc[m][n], 0, 0, 0);
  }

  // ---- V^T epilogue (z==2): coalesced write of Vt[b][d][s] through LDS.
  // 4 rounds of 32 d x 128 tokens. Wave owns d in [wn, wn+64): waves with
  // wn==0 serve rounds 0,1; wn==64 serve rounds 2,3; n = 2*(r&1)+j.
  if (VT_Z2 && z == 2) {
    const int bb = m0 >> 11, s0 = m0 & 2047;  // 128-token run stays in one b
#pragma unroll
    for (int r = 0; r < 4; r++) {
      __syncthreads();  // LDS free (main-loop reads / prev round done)
      if ((wn == 0) == (r < 2)) {
#pragma unroll
        for (int j = 0; j < 2; j++) {
          const int n = 2 * (r & 1) + j;
          const int dloc = j * 16 + r16;               // d - r*32
          const float bv = bias[n0 + wn + n * 16 + r16];
#pragma unroll
          for (int m = 0; m < MT_; m++) {
            const int tok = wm + m * 16 + quad * 4;    // 4 consecutive tokens
            ushort4 o;
            o.x = f2bf(acc[m][n][0] + bv);
            o.y = f2bf(acc[m][n][1] + bv);
            o.z = f2bf(acc[m][n][2] + bv);
            o.w = f2bf(acc[m][n][3] + bv);
            *(ushort4*)(smemAB + dloc * 136 + tok) = o;
          }
        }
      }
      __syncthreads();
      // stream out: 32 rows x 256B, 8 threads/row x 32B -> fully coalesced
      const int row = tid >> 3, off = (tid & 7) * 16;
      const int d = n0 + r * 32 + row;
      ushort_t* dst = vt_out + ((size_t)bb * Dd + d) * Ss + s0 + off;
      const uint4 w0 = *(const uint4*)(smemAB + row * 136 + off);
      const uint4 w1 = *(const uint4*)(smemAB + row * 136 + off + 8);
      *(uint4*)dst = w0;
      *(uint4*)(dst + 8) = w1;
    }
    return;
  }

  // epilogue: C/D layout col=lane&15, row=quad*4+reg
#pragma unroll
  for (int m = 0; m < MT_; m++) {
#pragma unroll
    for (int n = 0; n < NT_; n++) {
      const int gc = n0 + wn + n * 16 + r16;
      const float bv = bias[gc];
#pragma unroll
      for (int r = 0; r < 4; r++) {
        const int gr = m0 + wm + m * 16 + quad * 4 + r;
        const float v = (acc[m][n][r] + bv) * sc;
        if (OUT_BF16)
          ((ushort_t*)Cbase)[(size_t)z * c_stride + (size_t)gr * Nn + gc] = f2bf(v);
        else
          ((float*)Cbase)[(size_t)z * c_stride + (size_t)gr * Nn + gc] = v;
      }
    }
  }
}

// ---------------------------------------------------------------------------
// MFMA flash attention v12 (proven best: 56.5us steady-state). v13's
// barrier-free variant was neutral-minus; register-resident K/V variants
// (v6-v9) spill or collapse the vmcnt pipeline. Structure:
//  - K staging WAVE-LOCAL, single buffer, no barrier (lgkmcnt proof).
//  - V single buffer with barrier pair around PV; symmetric counted
//    vmcnt(4) waits; prefetch never drained.
// LDS = 16KB K + 16KB V, union 34816B reduction. __launch_bounds__(256,3):
// unified VGPR+AGPR cap 170 >= ~148 live ((256,4)=cap 128 spills — v11).
// ---------------------------------------------------------------------------
__global__ __launch_bounds__(256, 3) void flash_mfma(
    const ushort_t* __restrict__ Qp, const ushort_t* __restrict__ Kp,
    const ushort_t* __restrict__ Vt, ushort_t* __restrict__ Xp) {
  __shared__ __align__(16) char smem[34816];
  ushort_t* KsU = (ushort_t*)smem;        // K pair staging (u16 idx 0..8191)
  ushort_t* VtsU = KsU + 8192;            // V pair staging (u16 idx 0..8191)
  float* red = (float*)smem;              // reduction union

  const int tid = threadIdx.x, lane = tid & 63, wid = tid >> 6;
  // XCD-bijective swizzle: nwg=1024, 8 XCDs, 128 blocks/XCD = 4 (b,h) groups
  const int lid = blockIdx.x + (blockIdx.y << 5) + (blockIdx.z << 9);
  const int swzb = ((lid & 7) << 7) + (lid >> 3);
  const int qt = swzb & 31, h = (swzb >> 5) & 15, b = swzb >> 9;
  const int quad = lane >> 4, r16 = lane & 15;
  const int row8 = lane >> 3;                       // staging row in 8-row chunk
  const int colsw = ((lane & 7) ^ row8) * 8;        // swizzled source col (u16)
  const int swz = r16 & 7;                          // read-side swizzle key

  const ushort_t* Qg = Qp + ((size_t)(b * Ss + qt * 64)) * Dd + h * 64;
  const ushort_t* Kg = Kp + ((size_t)b * Ss) * Dd + h * 64;
  const ushort_t* Vg = Vt + ((size_t)b * Dd + h * 64) * Ss;  // rows d, stride S

  // Q fragments for ALL 64 qrows (B-operand): qf[ks][n] = Q[n*16+r16][ks*32+quad*8..]
  bf16x8 qf[2][4];
#pragma unroll
  for (int n = 0; n < 4; n++)
#pragma unroll
    for (int ks = 0; ks < 2; ks++)
      qf[ks][n] = *(const bf16x8*)(Qg + (size_t)(n * 16 + r16) * Dd + ks * 32 + quad * 8);

  // read offsets (u16 units), loop-invariant
  const uint32_t kbase = (uint32_t)(wid * 16 + r16) * 64;
  const uint32_t ko0 = (uint32_t)((quad ^ swz) << 3);
  const uint32_t ko1 = (uint32_t)(((4 + quad) ^ swz) << 3);
  const int vG = wid * 2 + (quad >> 1);
  const uint32_t vcol = (uint32_t)(((vG ^ swz) << 3) + (quad & 1) * 4);

  f32x4 acc[4][4];  // [mt d-tile][n qrow-tile], partial over this wave's keys
#pragma unroll
  for (int mt = 0; mt < 4; mt++)
#pragma unroll
    for (int n = 0; n < 4; n++) acc[mt][n] = f32x4{0.f, 0.f, 0.f, 0.f};
  float rsn[4] = {0.f, 0.f, 0.f, 0.f};  // rowsum partials per qrow-tile

  constexpr int NP = Ss / 128;  // 16 pairs

  // stage pair pr's K (4 loads/wave; chunks are WAVE-LOCAL: keys 16w..16w+16)
  auto stageK = [&](int pr) {
#pragma unroll
    for (int s = 0; s < 2; s++) {
      const int t64 = pr * 2 + s;
#pragma unroll
      for (int i = 0; i < 2; i++) {
        const int I = wid * 2 + i;
        load16_lds(Kg + (size_t)(t64 * 64 + I * 8 + row8) * Dd + colsw,
                   KsU + s * 4096 + I * 512);
      }
    }
  };
  // stage pair pr's V (4 loads/wave; cross-wave consumers -> barrier protocol)
  auto stageV = [&](int pr) {
#pragma unroll
    for (int s = 0; s < 2; s++) {
      const int t64 = pr * 2 + s;
#pragma unroll
      for (int i = 0; i < 2; i++) {
        const int I = wid * 2 + i;
        load16_lds(Vg + (size_t)(I * 8 + row8) * Ss + t64 * 64 + colsw,
                   VtsU + s * 4096 + I * 512);
      }
    }
  };

  // prologue: stage pair 0 (K then V), drain everything, make V visible
  stageK(0);
  stageV(0);
  asm volatile("s_waitcnt vmcnt(0)" ::: "memory");
  __syncthreads();

  const ushort_t* KcA = KsU;
  const ushort_t* KcB = KsU + 4096;
  const ushort_t* VcA = VtsU;
  const ushort_t* VcB = VtsU + 4096;

  for (int p = 0; p < NP; p++) {
    // K(p) landed (queue: K(p)x4 old, V(p)x4 new -> vmcnt(4) keeps V in flight)
    asm volatile("s_waitcnt vmcnt(4)" ::: "memory");

    // K fragments for both subtiles (ds_read_b128 x4, wave-local chunks)
    const bf16x8 kfA0 = *(const bf16x8*)(KcA + kbase + ko0);
    const bf16x8 kfA1 = *(const bf16x8*)(KcA + kbase + ko1);
    const bf16x8 kfB0 = *(const bf16x8*)(KcB + kbase + ko0);
    const bf16x8 kfB1 = *(const bf16x8*)(KcB + kbase + ko1);

    // ---- QK^T subtile A: S[key][qrow], key = quad*4+reg (wave's 16 keys)
    f32x4 sacc[4];
#pragma unroll
    for (int n = 0; n < 4; n++) sacc[n] = f32x4{0.f, 0.f, 0.f, 0.f};
    __builtin_amdgcn_s_setprio(1);
#pragma unroll
    for (int n = 0; n < 4; n++)
      sacc[n] = __builtin_amdgcn_mfma_f32_16x16x32_bf16(kfA0, qf[0][n], sacc[n], 0, 0, 0);
#pragma unroll
    for (int n = 0; n < 4; n++)
      sacc[n] = __builtin_amdgcn_mfma_f32_16x16x32_bf16(kfA1, qf[1][n], sacc[n], 0, 0, 0);
    __builtin_amdgcn_s_setprio(0);

    // softmax A -> packed low half of pf
    uint2 pA[4];
#pragma unroll
    for (int n = 0; n < 4; n++) {
      const float p0 = EXP2F(sacc[n][0]), p1 = EXP2F(sacc[n][1]);
      const float p2 = EXP2F(sacc[n][2]), p3 = EXP2F(sacc[n][3]);
      rsn[n] += (p0 + p1) + (p2 + p3);
      union { __hip_bfloat162 hh; unsigned u; } lo, hi;
      lo.hh = __float22bfloat162_rn(make_float2(p0, p1));
      hi.hh = __float22bfloat162_rn(make_float2(p2, p3));
      pA[n] = make_uint2(lo.u, hi.u);
    }

    // ---- QK^T subtile B
#pragma unroll
    for (int n = 0; n < 4; n++) sacc[n] = f32x4{0.f, 0.f, 0.f, 0.f};
    __builtin_amdgcn_s_setprio(1);
#pragma unroll
    for (int n = 0; n < 4; n++)
      sacc[n] = __builtin_amdgcn_mfma_f32_16x16x32_bf16(kfB0, qf[0][n], sacc[n], 0, 0, 0);
#pragma unroll
    for (int n = 0; n < 4; n++)
      sacc[n] = __builtin_amdgcn_mfma_f32_16x16x32_bf16(kfB1, qf[1][n], sacc[n], 0, 0, 0);
    __builtin_amdgcn_s_setprio(0);

    // kf consumed (compiler lgkmcnt drained before the MFMAs above) ->
    // safe to overwrite the K buffer; prefetch next pair's K (wave-local).
    stageK((p + 1) & (NP - 1));

    // softmax B + assemble K=32 P fragments: bf16x8 elem j <-> k=quad*8+j;
    // j=0..3 keys of subtile A (quad*4+j), j=4..7 keys of subtile B.
    bf16x8 pf[4];
#pragma unroll
    for (int n = 0; n < 4; n++) {
      const float p0 = EXP2F(sacc[n][0]), p1 = EXP2F(sacc[n][1]);
      const float p2 = EXP2F(sacc[n][2]), p3 = EXP2F(sacc[n][3]);
      rsn[n] += (p0 + p1) + (p2 + p3);
      union { __hip_bfloat162 hh; unsigned u; } lo, hi;
      lo.hh = __float22bfloat162_rn(make_float2(p0, p1));
      hi.hh = __float22bfloat162_rn(make_float2(p2, p3));
      union { uint4 u; bf16x8 v; } pk;
      pk.u = make_uint4(pA[n].x, pA[n].y, lo.u, hi.u);
      pf[n] = pk.v;
    }

    // V(p) landed (queue: V(p)x4 old, K(p+1)x4 new -> vmcnt(4)); barrier
    // makes all waves' V(p) visible. K(p+1) prefetch stays in flight.
    asm volatile("s_waitcnt vmcnt(4)\n\ts_barrier" ::: "memory");

    // ---- PV: Ot[d][qrow] += V^T[:, 32 keys] @ P (K=32); V from LDS (b64)
    __builtin_amdgcn_s_setprio(1);
#pragma unroll
    for (int mt = 0; mt < 4; mt++) {
      const uint2 vA = *(const uint2*)(VcA + (uint32_t)(mt * 16 + r16) * 64 + vcol);
      const uint2 vB = *(const uint2*)(VcB + (uint32_t)(mt * 16 + r16) * 64 + vcol);
      union { uint4 u; bf16x8 v; } vk;
      vk.u = make_uint4(vA.x, vA.y, vB.x, vB.y);
#pragma unroll
      for (int n = 0; n < 4; n++)
        acc[mt][n] = __builtin_amdgcn_mfma_f32_16x16x32_bf16(vk.v, pf[n], acc[mt][n], 0, 0, 0);
    }
    __builtin_amdgcn_s_setprio(0);

    // all waves' vf reads done (lgkmcnt drained before their MFMAs) ->
    // barrier licenses overwriting V; stage next pair's V last.
    asm volatile("s_barrier" ::: "memory");
    stageV((p + 1) & (NP - 1));
  }

  // drain the wrapped V(0) stage before the reduction reuses this LDS
  asm volatile("s_waitcnt vmcnt(0)" ::: "memory");

  // ---- in-wave quad combine of rowsums (same qrow, different keys) ----
#pragma unroll
  for (int n = 0; n < 4; n++) {
    float r = rsn[n];
    r += __shfl_xor(r, 16, 64);
    r += __shfl_xor(r, 32, 64);
    rsn[n] = r;
  }

  // ---- cross-wave tree reduction through LDS (padded 68-f32 rows) ----
  __syncthreads();
  if (wid & 2) {  // waves 2,3 -> slots 0,1
    float* p = red + (size_t)(wid & 1) * (64 * 68) + (size_t)lane * 68;
#pragma unroll
    for (int mt = 0; mt < 4; mt++)
#pragma unroll
      for (int n = 0; n < 4; n++)
        *(f32x4*)(p + (mt * 4 + n) * 4) = acc[mt][n];
    p[64] = rsn[0]; p[65] = rsn[1]; p[66] = rsn[2]; p[67] = rsn[3];
  }
  __syncthreads();
  if (!(wid & 2)) {  // wave0+=slot0(wave2), wave1+=slot1(wave3)
    const float* p = red + (size_t)wid * (64 * 68) + (size_t)lane * 68;
#pragma unroll
    for (int mt = 0; mt < 4; mt++)
#pragma unroll
      for (int n = 0; n < 4; n++)
        acc[mt][n] += *(const f32x4*)(p + (mt * 4 + n) * 4);
    rsn[0] += p[64]; rsn[1] += p[65]; rsn[2] += p[66]; rsn[3] += p[67];
  }
  __syncthreads();
  if (wid == 1) {
    float* p = red + (size_t)lane * 68;
#pragma unroll
    for (int mt = 0; mt < 4; mt++)
#pragma unroll
      for (int n = 0; n < 4; n++)
        *(f32x4*)(p + (mt * 4 + n) * 4) = acc[mt][n];
    p[64] = rsn[0]; p[65] = rsn[1]; p[66] = rsn[2]; p[67] = rsn[3];
  }
  __syncthreads();
  if (wid == 0) {
    const float* p = red + (size_t)lane * 68;
#pragma unroll
    for (int mt = 0; mt < 4; mt++)
#pragma unroll
      for (int n = 0; n < 4; n++)
        acc[mt][n] += *(const f32x4*)(p + (mt * 4 + n) * 4);
    rsn[0] += p[64]; rsn[1] += p[65]; rsn[2] += p[66]; rsn[3] += p[67];
    float inv[4];
#pragma unroll
    for (int n = 0; n < 4; n++) inv[n] = 1.0f / rsn[n];
    // write X: d = mt*16+quad*4+reg (contiguous reg), qrow = n*16+r16
#pragma unroll
    for (int mt = 0; mt < 4; mt++) {
#pragma unroll
      for (int n = 0; n < 4; n++) {
        ushort4 o;
        o.x = f2bf(acc[mt][n][0] * inv[n]);
        o.y = f2bf(acc[mt][n][1] * inv[n]);
        o.z = f2bf(acc[mt][n][2] * inv[n]);
        o.w = f2bf(acc[mt][n][3] * inv[n]);
        *(ushort4*)(Xp + (size_t)(b * Ss + qt * 64 + n * 16 + r16) * Dd +
                    h * 64 + mt * 16 + quad * 4) = o;
      }
    }
  }
}

// ---------------------------------------------------------------------------
extern "C" void kernel_launch(void* const* d_in, const int* in_sizes, int n_in,
                              void* d_out, int out_size, void* d_ws,
                              size_t ws_size, hipStream_t stream) {
  const float* q  = (const float*)d_in[0];
  const float* k  = (const float*)d_in[1];
  const float* v  = (const float*)d_in[2];
  const float* Wq = (const float*)d_in[3];
  const float* bq = (const float*)d_in[4];
  const float* Wk = (const float*)d_in[5];
  const float* bk = (const float*)d_in[6];
  const float* Wv = (const float*)d_in[7];
  const float* bv = (const float*)d_in[8];
  const float* Wo = (const float*)d_in[9];
  const float* bo = (const float*)d_in[10];

  ushort_t* ws = (ushort_t*)d_ws;
  const size_t MD = (size_t)Mm * Kk;  // 4,194,304
  const size_t KN = (size_t)Kk * Nn;  // 1,048,576
  ushort_t* qkvb = ws;                // 3*MD   bf16 inputs
  ushort_t* Wt   = ws + 3 * MD;       // 4*KN   transposed weights
  ushort_t* QKVp = Wt + 4 * KN;       // 3*MD   Q,K projections (V slot unused)
  ushort_t* Vtp  = QKVp + 3 * MD;     // MD     V^T per head (written by gemm)
  ushort_t* Xp   = qkvb;              // reuse: qkvb dead after QKV GEMMs

  prep<<<dim3(13312), 256, 0, stream>>>(q, k, v, qkvb, Wq, Wk, Wv, Wo, Wt);
  gemm_mfma<128, true, true><<<dim3(Nn / 128, Mm / 128, 3), 256, 0, stream>>>(
      qkvb, MD, Wt, KN, bq, bk, bv, QKVp, MD, QSCALE, Vtp);
  flash_mfma<<<dim3(Ss / 64, Hh, Bb), 256, 0, stream>>>(QKVp, QKVp + MD, Vtp, Xp);
  gemm_mfma<64, false, false><<<dim3(Nn / 64, Mm / 128, 1), 256, 0, stream>>>(
      Xp, 0, Wt + 3 * KN, 0, bo, bo, bo, d_out, 0, 1.0f, nullptr);
}

// Round 13
// 226.818 us; speedup vs baseline: 1.0367x; 1.0367x over previous
//
#include <hip/hip_runtime.h>
#include <hip/hip_bf16.h>
#include <math.h>
#include <stdint.h>

// Problem constants: B=2, S=2048, D=1024, H=16, DK=64
constexpr int Bb = 2, Ss = 2048, Dd = 1024, Hh = 16;
constexpr int Mm = Bb * Ss;  // 4096 (GEMM M)
constexpr int Nn = Dd;       // 1024
constexpr int Kk = Dd;       // 1024
// fold 1/sqrt(DK) and log2(e) into Q so the softmax uses exp2
constexpr float QSCALE = 0.125f * 1.44269504088896340736f;

typedef unsigned short ushort_t;
typedef __attribute__((ext_vector_type(8))) short bf16x8;   // K=32 A/B frag
typedef __attribute__((ext_vector_type(4))) float f32x4;    // 16x16 C/D frag

#if __has_builtin(__builtin_amdgcn_exp2f)
#define EXP2F(x) __builtin_amdgcn_exp2f(x)
#else
#define EXP2F(x) exp2f(x)
#endif

__device__ __forceinline__ ushort_t f2bf(float f) {  // round-to-nearest-even
  union { float f; unsigned u; } v; v.f = f;
  return (ushort_t)((v.u + 0x7fff + ((v.u >> 16) & 1)) >> 16);
}

// async global->LDS, 16B per lane; LDS dest is wave-uniform base + lane*16
__device__ __forceinline__ void load16_lds(const void* g, void* l) {
  __builtin_amdgcn_global_load_lds(
      (const __attribute__((address_space(1))) void*)(uintptr_t)g,
      (__attribute__((address_space(3))) void*)(uint32_t)(uintptr_t)l, 16, 0, 0);
}

// ---------------------------------------------------------------------------
// Merged prep pass (one dispatch):
//  blocks [0, 12288): fp32->bf16 convert of q,k,v  (z = bid/4096)
//  blocks [12288, 13312): W [K][N] fp32 -> Wt [N][K] bf16 transpose
// ---------------------------------------------------------------------------
__global__ __launch_bounds__(256) void prep(
    const float* __restrict__ q, const float* __restrict__ k,
    const float* __restrict__ v, ushort_t* __restrict__ qkvb,
    const float* __restrict__ Wq, const float* __restrict__ Wk,
    const float* __restrict__ Wv, const float* __restrict__ Wo,
    ushort_t* __restrict__ Wt) {
  const int bid = blockIdx.x;
  const int tid = threadIdx.x;
  if (bid < 12288) {  // ---- convert q/k/v ----
    const int z = bid >> 12, xi = bid & 4095;
    const float* src = (z == 0) ? q : (z == 1) ? k : v;
    ushort_t* dst = qkvb + (size_t)z * Mm * Kk;
    const size_t idx = ((size_t)xi * 256 + tid) * 4;
    const float4 val = *(const float4*)(src + idx);
    ushort4 o;
    o.x = f2bf(val.x); o.y = f2bf(val.y); o.z = f2bf(val.z); o.w = f2bf(val.w);
    *(ushort4*)(dst + idx) = o;
    return;
  }
  // ---- transpose weights ----
  const int bid2 = bid - 12288;
  const int z = bid2 >> 8, rem = bid2 & 255;
  const float* W = (z == 0) ? Wq : (z == 1) ? Wk : (z == 2) ? Wv : Wo;
  ushort_t* out = Wt + (size_t)z * Kk * Nn;
  __shared__ float t[64][65];
  const int n0 = (rem & 15) * 64, k0 = (rem >> 4) * 64;
  const int lr = tid >> 4, lc = (tid & 15) * 4;
#pragma unroll
  for (int i = 0; i < 4; i++) {
    const int r = lr + i * 16;
    const float4 vv = *(const float4*)(W + (size_t)(k0 + r) * Nn + n0 + lc);
    t[r][lc] = vv.x; t[r][lc + 1] = vv.y; t[r][lc + 2] = vv.z; t[r][lc + 3] = vv.w;
  }
  __syncthreads();
  const int n = tid >> 2, kc = (tid & 3) * 16;
  ushort_t tmp[16];
#pragma unroll
  for (int j = 0; j < 16; j++) tmp[j] = f2bf(t[kc + j][n]);
  ushort_t* op = out + (size_t)(n0 + n) * Kk + k0 + kc;
  ((uint4*)op)[0] = ((uint4*)tmp)[0];
  ((uint4*)op)[1] = ((uint4*)tmp)[1];
}

// ---------------------------------------------------------------------------
// Vp [B*S][D] bf16 -> Vt [B][D][S] bf16  (PV A-operand wants V^T rows)
// v14/v15 fused this into the GEMM epilogue (scatter / LDS-transpose) —
// both cost the same ~10us they saved. Separate coalesced kernel restored.
// ---------------------------------------------------------------------------
__global__ __launch_bounds__(256) void transpose_v(
    const ushort_t* __restrict__ Vp, ushort_t* __restrict__ Vt) {
  __shared__ ushort_t t[64][68];
  const int tid = threadIdx.x;
  const int s0 = blockIdx.x * 64, h = blockIdx.y, b = blockIdx.z;
  const int lr = tid >> 4, lc = (tid & 15) * 4;
#pragma unroll
  for (int i = 0; i < 4; i++) {
    const int r = lr + i * 16;
    const ushort4 v =
        *(const ushort4*)(Vp + (size_t)(b * Ss + s0 + r) * Dd + h * 64 + lc);
    *(ushort4*)&t[r][lc] = v;
  }
  __syncthreads();
  const int d = tid >> 2, sc = (tid & 3) * 16;
  ushort_t tmp[16];
#pragma unroll
  for (int j = 0; j < 16; j++) tmp[j] = t[sc + j][d];
  ushort_t* op = Vt + ((size_t)b * Dd + h * 64 + d) * Ss + s0 + sc;
  ((uint4*)op)[0] = ((uint4*)tmp)[0];
  ((uint4*)op)[1] = ((uint4*)tmp)[1];
}

// ---------------------------------------------------------------------------
// bf16 MFMA GEMM v16: m97 recipe + the v10/v12-PROVEN counted-vmcnt dbuf.
// v15 counters: QKV gemm 66.8us with MfmaUtil 14.6 / VALU 9.3 / HBM 12 /
// occ 17 — all low = latency-bound. Cause: the old loop's second
// __syncthreads forces compiler vmcnt(0) on the JUST-issued staging loads;
// a full L2 latency is exposed serially in each of 32 K-iters with only
// ~3 blocks/CU to cover it. Fix (flash-v10 protocol, HW-verified): double
// buffer; stage tile k+1 into buf^1, wait vmcnt(L) (tile k+1's L loads
// stay in flight across BOTH barriers), compute buf[cur], end barrier
// licenses next overwrite. L = per-wave loads = BM/64 + BN/64.
// XCD-aware (x,y) swizzle kept (bijective, nxy%8==0).
// ---------------------------------------------------------------------------
template <int BN, bool OUT_BF16>
__global__ __launch_bounds__(256) void gemm_mfma(
    const ushort_t* __restrict__ Abase, size_t a_stride,
    const ushort_t* __restrict__ Wbase, size_t w_stride,
    const float* __restrict__ bias0, const float* __restrict__ bias1,
    const float* __restrict__ bias2, void* __restrict__ Cbase, size_t c_stride,
    float scale_z0) {
  constexpr int BM = 128, BK = 32;
  constexpr int WM = (BN == 128) ? 64 : 32;  // wave tile
  constexpr int MT_ = WM / 16, NT_ = 4;      // WN = 64 always
  constexpr int NKT = Kk / BK;               // 32 K-tiles
  constexpr int LA = BM / 64, LB = BN / 64;  // staging insts per wave
  __shared__ ushort_t As[2][BM * BK];
  __shared__ ushort_t Bs[2][BN * BK];
  const int tid = threadIdx.x, lane = tid & 63, wid = tid >> 6;
  const int z = blockIdx.z;
  const ushort_t* A = Abase + (size_t)z * a_stride;
  const ushort_t* Wt = Wbase + (size_t)z * w_stride;
  const float* bias = (z == 0) ? bias0 : (z == 1) ? bias1 : bias2;
  const float sc = (z == 0) ? scale_z0 : 1.0f;
  // XCD-aware swizzle (bijective: nxy % 8 == 0)
  const int nxy = gridDim.x * gridDim.y;
  const int lid0 = blockIdx.x + gridDim.x * blockIdx.y;
  const int cpx = nxy >> 3;
  const int swb = (lid0 & 7) * cpx + (lid0 >> 3);
  const int m0 = (swb / gridDim.x) * BM, n0 = (swb % gridDim.x) * BN;
  const int wm = (BN == 128) ? (wid >> 1) * 64 : wid * 32;
  const int wn = (BN == 128) ? (wid & 1) * 64 : 0;
  const int quad = lane >> 4, r16 = lane & 15;
  const int srow = lane >> 2;        // staging: 16 rows/inst
  const int scol = (lane & 3) * 8;   // 4 lanes x 16B per 64B row

  f32x4 acc[MT_][NT_];
#pragma unroll
  for (int m = 0; m < MT_; m++)
#pragma unroll
    for (int n = 0; n < NT_; n++) acc[m][n] = f32x4{0.f, 0.f, 0.f, 0.f};

  // stage K-tile kt into buffer bsel (LA+LB global_load_lds per wave)
  auto stage = [&](int kt, int bsel) {
    const int k0 = kt * BK;
#pragma unroll
    for (int i = 0; i < LA; i++) {
      const int I = wid * LA + i;
      load16_lds(A + (size_t)(m0 + I * 16 + srow) * Kk + k0 + scol,
                 &As[bsel][I * 512]);
    }
#pragma unroll
    for (int i = 0; i < LB; i++) {
      const int I = wid * LB + i;
      load16_lds(Wt + (size_t)(n0 + I * 16 + srow) * Kk + k0 + scol,
                 &Bs[bsel][I * 512]);
    }
  };

  // prologue: stage tile 0, drain, sync
  stage(0, 0);
  asm volatile("s_waitcnt vmcnt(0)" ::: "memory");
  __syncthreads();

  for (int kt = 0; kt < NKT; kt++) {
    const int cur = kt & 1;
    if (kt + 1 < NKT) {
      stage(kt + 1, cur ^ 1);  // L loads stay in flight across both barriers
      if constexpr (LA + LB == 4)
        asm volatile("s_waitcnt vmcnt(4)\n\ts_barrier" ::: "memory");
      else
        asm volatile("s_waitcnt vmcnt(3)\n\ts_barrier" ::: "memory");
    } else {
      asm volatile("s_waitcnt vmcnt(0)\n\ts_barrier" ::: "memory");
    }

    bf16x8 af[MT_], bfr[NT_];
#pragma unroll
    for (int m = 0; m < MT_; m++)
      af[m] = *(const bf16x8*)(&As[cur][(wm + m * 16 + r16) * BK + quad * 8]);
#pragma unroll
    for (int n = 0; n < NT_; n++)
      bfr[n] = *(const bf16x8*)(&Bs[cur][(wn + n * 16 + r16) * BK + quad * 8]);
    __builtin_amdgcn_s_setprio(1);
#pragma unroll
    for (int m = 0; m < MT_; m++)
#pragma unroll
      for (int n = 0; n < NT_; n++)
        acc[m][n] =
            __builtin_amdgcn_mfma_f32_16x16x32_bf16(af[m], bfr[n], acc[m][n], 0, 0, 0);
    __builtin_amdgcn_s_setprio(0);

    // ds_reads above are consumed (lgkmcnt before MFMA) -> barrier licenses
    // next iter's stage into buf[cur] without draining its loads.
    asm volatile("s_barrier" ::: "memory");
  }

  // epilogue: C/D layout col=lane&15, row=quad*4+reg
#pragma unroll
  for (int m = 0; m < MT_; m++) {
#pragma unroll
    for (int n = 0; n < NT_; n++) {
      const int gc = n0 + wn + n * 16 + r16;
      const float bv = bias[gc];
#pragma unroll
      for (int r = 0; r < 4; r++) {
        const int gr = m0 + wm + m * 16 + quad * 4 + r;
        const float v = (acc[m][n][r] + bv) * sc;
        if (OUT_BF16)
          ((ushort_t*)Cbase)[(size_t)z * c_stride + (size_t)gr * Nn + gc] = f2bf(v);
        else
          ((float*)Cbase)[(size_t)z * c_stride + (size_t)gr * Nn + gc] = v;
      }
    }
  }
}

// ---------------------------------------------------------------------------
// MFMA flash attention v12 (proven best: 56.5us steady-state).
//  - K staging WAVE-LOCAL, single buffer, no barrier (lgkmcnt proof).
//  - V single buffer with barrier pair around PV; symmetric counted
//    vmcnt(4) waits; prefetch never drained.
// LDS = 16KB K + 16KB V, union 34816B reduction. __launch_bounds__(256,3):
// unified VGPR+AGPR cap 170 >= ~148 live ((256,4)=cap 128 spills — v11).
// ---------------------------------------------------------------------------
__global__ __launch_bounds__(256, 3) void flash_mfma(
    const ushort_t* __restrict__ Qp, const ushort_t* __restrict__ Kp,
    const ushort_t* __restrict__ Vt, ushort_t* __restrict__ Xp) {
  __shared__ __align__(16) char smem[34816];
  ushort_t* KsU = (ushort_t*)smem;        // K pair staging (u16 idx 0..8191)
  ushort_t* VtsU = KsU + 8192;            // V pair staging (u16 idx 0..8191)
  float* red = (float*)smem;              // reduction union

  const int tid = threadIdx.x, lane = tid & 63, wid = tid >> 6;
  // XCD-bijective swizzle: nwg=1024, 8 XCDs, 128 blocks/XCD = 4 (b,h) groups
  const int lid = blockIdx.x + (blockIdx.y << 5) + (blockIdx.z << 9);
  const int swzb = ((lid & 7) << 7) + (lid >> 3);
  const int qt = swzb & 31, h = (swzb >> 5) & 15, b = swzb >> 9;
  const int quad = lane >> 4, r16 = lane & 15;
  const int row8 = lane >> 3;                       // staging row in 8-row chunk
  const int colsw = ((lane & 7) ^ row8) * 8;        // swizzled source col (u16)
  const int swz = r16 & 7;                          // read-side swizzle key

  const ushort_t* Qg = Qp + ((size_t)(b * Ss + qt * 64)) * Dd + h * 64;
  const ushort_t* Kg = Kp + ((size_t)b * Ss) * Dd + h * 64;
  const ushort_t* Vg = Vt + ((size_t)b * Dd + h * 64) * Ss;  // rows d, stride S

  // Q fragments for ALL 64 qrows (B-operand): qf[ks][n] = Q[n*16+r16][ks*32+quad*8..]
  bf16x8 qf[2][4];
#pragma unroll
  for (int n = 0; n < 4; n++)
#pragma unroll
    for (int ks = 0; ks < 2; ks++)
      qf[ks][n] = *(const bf16x8*)(Qg + (size_t)(n * 16 + r16) * Dd + ks * 32 + quad * 8);

  // read offsets (u16 units), loop-invariant
  const uint32_t kbase = (uint32_t)(wid * 16 + r16) * 64;
  const uint32_t ko0 = (uint32_t)((quad ^ swz) << 3);
  const uint32_t ko1 = (uint32_t)(((4 + quad) ^ swz) << 3);
  const int vG = wid * 2 + (quad >> 1);
  const uint32_t vcol = (uint32_t)(((vG ^ swz) << 3) + (quad & 1) * 4);

  f32x4 acc[4][4];  // [mt d-tile][n qrow-tile], partial over this wave's keys
#pragma unroll
  for (int mt = 0; mt < 4; mt++)
#pragma unroll
    for (int n = 0; n < 4; n++) acc[mt][n] = f32x4{0.f, 0.f, 0.f, 0.f};
  float rsn[4] = {0.f, 0.f, 0.f, 0.f};  // rowsum partials per qrow-tile

  constexpr int NP = Ss / 128;  // 16 pairs

  // stage pair pr's K (4 loads/wave; chunks are WAVE-LOCAL: keys 16w..16w+16)
  auto stageK = [&](int pr) {
#pragma unroll
    for (int s = 0; s < 2; s++) {
      const int t64 = pr * 2 + s;
#pragma unroll
      for (int i = 0; i < 2; i++) {
        const int I = wid * 2 + i;
        load16_lds(Kg + (size_t)(t64 * 64 + I * 8 + row8) * Dd + colsw,
                   KsU + s * 4096 + I * 512);
      }
    }
  };
  // stage pair pr's V (4 loads/wave; cross-wave consumers -> barrier protocol)
  auto stageV = [&](int pr) {
#pragma unroll
    for (int s = 0; s < 2; s++) {
      const int t64 = pr * 2 + s;
#pragma unroll
      for (int i = 0; i < 2; i++) {
        const int I = wid * 2 + i;
        load16_lds(Vg + (size_t)(I * 8 + row8) * Ss + t64 * 64 + colsw,
                   VtsU + s * 4096 + I * 512);
      }
    }
  };

  // prologue: stage pair 0 (K then V), drain everything, make V visible
  stageK(0);
  stageV(0);
  asm volatile("s_waitcnt vmcnt(0)" ::: "memory");
  __syncthreads();

  const ushort_t* KcA = KsU;
  const ushort_t* KcB = KsU + 4096;
  const ushort_t* VcA = VtsU;
  const ushort_t* VcB = VtsU + 4096;

  for (int p = 0; p < NP; p++) {
    // K(p) landed (queue: K(p)x4 old, V(p)x4 new -> vmcnt(4) keeps V in flight)
    asm volatile("s_waitcnt vmcnt(4)" ::: "memory");

    // K fragments for both subtiles (ds_read_b128 x4, wave-local chunks)
    const bf16x8 kfA0 = *(const bf16x8*)(KcA + kbase + ko0);
    const bf16x8 kfA1 = *(const bf16x8*)(KcA + kbase + ko1);
    const bf16x8 kfB0 = *(const bf16x8*)(KcB + kbase + ko0);
    const bf16x8 kfB1 = *(const bf16x8*)(KcB + kbase + ko1);

    // ---- QK^T subtile A: S[key][qrow], key = quad*4+reg (wave's 16 keys)
    f32x4 sacc[4];
#pragma unroll
    for (int n = 0; n < 4; n++) sacc[n] = f32x4{0.f, 0.f, 0.f, 0.f};
    __builtin_amdgcn_s_setprio(1);
#pragma unroll
    for (int n = 0; n < 4; n++)
      sacc[n] = __builtin_amdgcn_mfma_f32_16x16x32_bf16(kfA0, qf[0][n], sacc[n], 0, 0, 0);
#pragma unroll
    for (int n = 0; n < 4; n++)
      sacc[n] = __builtin_amdgcn_mfma_f32_16x16x32_bf16(kfA1, qf[1][n], sacc[n], 0, 0, 0);
    __builtin_amdgcn_s_setprio(0);

    // softmax A -> packed low half of pf
    uint2 pA[4];
#pragma unroll
    for (int n = 0; n < 4; n++) {
      const float p0 = EXP2F(sacc[n][0]), p1 = EXP2F(sacc[n][1]);
      const float p2 = EXP2F(sacc[n][2]), p3 = EXP2F(sacc[n][3]);
      rsn[n] += (p0 + p1) + (p2 + p3);
      union { __hip_bfloat162 hh; unsigned u; } lo, hi;
      lo.hh = __float22bfloat162_rn(make_float2(p0, p1));
      hi.hh = __float22bfloat162_rn(make_float2(p2, p3));
      pA[n] = make_uint2(lo.u, hi.u);
    }

    // ---- QK^T subtile B
#pragma unroll
    for (int n = 0; n < 4; n++) sacc[n] = f32x4{0.f, 0.f, 0.f, 0.f};
    __builtin_amdgcn_s_setprio(1);
#pragma unroll
    for (int n = 0; n < 4; n++)
      sacc[n] = __builtin_amdgcn_mfma_f32_16x16x32_bf16(kfB0, qf[0][n], sacc[n], 0, 0, 0);
#pragma unroll
    for (int n = 0; n < 4; n++)
      sacc[n] = __builtin_amdgcn_mfma_f32_16x16x32_bf16(kfB1, qf[1][n], sacc[n], 0, 0, 0);
    __builtin_amdgcn_s_setprio(0);

    // kf consumed (compiler lgkmcnt drained before the MFMAs above) ->
    // safe to overwrite the K buffer; prefetch next pair's K (wave-local).
    stageK((p + 1) & (NP - 1));

    // softmax B + assemble K=32 P fragments: bf16x8 elem j <-> k=quad*8+j;
    // j=0..3 keys of subtile A (quad*4+j), j=4..7 keys of subtile B.
    bf16x8 pf[4];
#pragma unroll
    for (int n = 0; n < 4; n++) {
      const float p0 = EXP2F(sacc[n][0]), p1 = EXP2F(sacc[n][1]);
      const float p2 = EXP2F(sacc[n][2]), p3 = EXP2F(sacc[n][3]);
      rsn[n] += (p0 + p1) + (p2 + p3);
      union { __hip_bfloat162 hh; unsigned u; } lo, hi;
      lo.hh = __float22bfloat162_rn(make_float2(p0, p1));
      hi.hh = __float22bfloat162_rn(make_float2(p2, p3));
      union { uint4 u; bf16x8 v; } pk;
      pk.u = make_uint4(pA[n].x, pA[n].y, lo.u, hi.u);
      pf[n] = pk.v;
    }

    // V(p) landed (queue: V(p)x4 old, K(p+1)x4 new -> vmcnt(4)); barrier
    // makes all waves' V(p) visible. K(p+1) prefetch stays in flight.
    asm volatile("s_waitcnt vmcnt(4)\n\ts_barrier" ::: "memory");

    // ---- PV: Ot[d][qrow] += V^T[:, 32 keys] @ P (K=32); V from LDS (b64)
    __builtin_amdgcn_s_setprio(1);
#pragma unroll
    for (int mt = 0; mt < 4; mt++) {
      const uint2 vA = *(const uint2*)(VcA + (uint32_t)(mt * 16 + r16) * 64 + vcol);
      const uint2 vB = *(const uint2*)(VcB + (uint32_t)(mt * 16 + r16) * 64 + vcol);
      union { uint4 u; bf16x8 v; } vk;
      vk.u = make_uint4(vA.x, vA.y, vB.x, vB.y);
#pragma unroll
      for (int n = 0; n < 4; n++)
        acc[mt][n] = __builtin_amdgcn_mfma_f32_16x16x32_bf16(vk.v, pf[n], acc[mt][n], 0, 0, 0);
    }
    __builtin_amdgcn_s_setprio(0);

    // all waves' vf reads done (lgkmcnt drained before their MFMAs) ->
    // barrier licenses overwriting V; stage next pair's V last.
    asm volatile("s_barrier" ::: "memory");
    stageV((p + 1) & (NP - 1));
  }

  // drain the wrapped V(0) stage before the reduction reuses this LDS
  asm volatile("s_waitcnt vmcnt(0)" ::: "memory");

  // ---- in-wave quad combine of rowsums (same qrow, different keys) ----
#pragma unroll
  for (int n = 0; n < 4; n++) {
    float r = rsn[n];
    r += __shfl_xor(r, 16, 64);
    r += __shfl_xor(r, 32, 64);
    rsn[n] = r;
  }

  // ---- cross-wave tree reduction through LDS (padded 68-f32 rows) ----
  __syncthreads();
  if (wid & 2) {  // waves 2,3 -> slots 0,1
    float* p = red + (size_t)(wid & 1) * (64 * 68) + (size_t)lane * 68;
#pragma unroll
    for (int mt = 0; mt < 4; mt++)
#pragma unroll
      for (int n = 0; n < 4; n++)
        *(f32x4*)(p + (mt * 4 + n) * 4) = acc[mt][n];
    p[64] = rsn[0]; p[65] = rsn[1]; p[66] = rsn[2]; p[67] = rsn[3];
  }
  __syncthreads();
  if (!(wid & 2)) {  // wave0+=slot0(wave2), wave1+=slot1(wave3)
    const float* p = red + (size_t)wid * (64 * 68) + (size_t)lane * 68;
#pragma unroll
    for (int mt = 0; mt < 4; mt++)
#pragma unroll
      for (int n = 0; n < 4; n++)
        acc[mt][n] += *(const f32x4*)(p + (mt * 4 + n) * 4);
    rsn[0] += p[64]; rsn[1] += p[65]; rsn[2] += p[66]; rsn[3] += p[67];
  }
  __syncthreads();
  if (wid == 1) {
    float* p = red + (size_t)lane * 68;
#pragma unroll
    for (int mt = 0; mt < 4; mt++)
#pragma unroll
      for (int n = 0; n < 4; n++)
        *(f32x4*)(p + (mt * 4 + n) * 4) = acc[mt][n];
    p[64] = rsn[0]; p[65] = rsn[1]; p[66] = rsn[2]; p[67] = rsn[3];
  }
  __syncthreads();
  if (wid == 0) {
    const float* p = red + (size_t)lane * 68;
#pragma unroll
    for (int mt = 0; mt < 4; mt++)
#pragma unroll
      for (int n = 0; n < 4; n++)
        acc[mt][n] += *(const f32x4*)(p + (mt * 4 + n) * 4);
    rsn[0] += p[64]; rsn[1] += p[65]; rsn[2] += p[66]; rsn[3] += p[67];
    float inv[4];
#pragma unroll
    for (int n = 0; n < 4; n++) inv[n] = 1.0f / rsn[n];
    // write X: d = mt*16+quad*4+reg (contiguous reg), qrow = n*16+r16
#pragma unroll
    for (int mt = 0; mt < 4; mt++) {
#pragma unroll
      for (int n = 0; n < 4; n++) {
        ushort4 o;
        o.x = f2bf(acc[mt][n][0] * inv[n]);
        o.y = f2bf(acc[mt][n][1] * inv[n]);
        o.z = f2bf(acc[mt][n][2] * inv[n]);
        o.w = f2bf(acc[mt][n][3] * inv[n]);
        *(ushort4*)(Xp + (size_t)(b * Ss + qt * 64 + n * 16 + r16) * Dd +
                    h * 64 + mt * 16 + quad * 4) = o;
      }
    }
  }
}

// ---------------------------------------------------------------------------
extern "C" void kernel_launch(void* const* d_in, const int* in_sizes, int n_in,
                              void* d_out, int out_size, void* d_ws,
                              size_t ws_size, hipStream_t stream) {
  const float* q  = (const float*)d_in[0];
  const float* k  = (const float*)d_in[1];
  const float* v  = (const float*)d_in[2];
  const float* Wq = (const float*)d_in[3];
  const float* bq = (const float*)d_in[4];
  const float* Wk = (const float*)d_in[5];
  const float* bk = (const float*)d_in[6];
  const float* Wv = (const float*)d_in[7];
  const float* bv = (const float*)d_in[8];
  const float* Wo = (const float*)d_in[9];
  const float* bo = (const float*)d_in[10];

  ushort_t* ws = (ushort_t*)d_ws;
  const size_t MD = (size_t)Mm * Kk;  // 4,194,304
  const size_t KN = (size_t)Kk * Nn;  // 1,048,576
  ushort_t* qkvb = ws;                // 3*MD   bf16 inputs
  ushort_t* Wt   = ws + 3 * MD;       // 4*KN   transposed weights
  ushort_t* QKVp = Wt + 4 * KN;       // 3*MD   Q,K,V projections
  ushort_t* Vtp  = QKVp + 3 * MD;     // MD     V^T per head
  ushort_t* Xp   = qkvb;              // reuse: qkvb dead after QKV GEMMs

  prep<<<dim3(13312), 256, 0, stream>>>(q, k, v, qkvb, Wq, Wk, Wv, Wo, Wt);
  gemm_mfma<128, true><<<dim3(Nn / 128, Mm / 128, 3), 256, 0, stream>>>(
      qkvb, MD, Wt, KN, bq, bk, bv, QKVp, MD, QSCALE);
  transpose_v<<<dim3(Ss / 64, Hh, Bb), 256, 0, stream>>>(QKVp + 2 * MD, Vtp);
  flash_mfma<<<dim3(Ss / 64, Hh, Bb), 256, 0, stream>>>(QKVp, QKVp + MD, Vtp, Xp);
  gemm_mfma<64, false><<<dim3(Nn / 64, Mm / 128, 1), 256, 0, stream>>>(
      Xp, 0, Wt + 3 * KN, 0, bo, bo, bo, d_out, 0, 1.0f);
}